// Round 9
// baseline (523.609 us; speedup 1.0000x reference)
//
#include <hip/hip_runtime.h>
#include <math.h>

typedef unsigned short u16;
typedef unsigned int u32;
typedef __attribute__((ext_vector_type(8))) short bf16x8;
typedef __attribute__((ext_vector_type(4))) float f32x4;

#define S_LEN 2048
#define HID 4096
#define NH 32
#define NKV 8
#define HD 128
#define QS 6144  // fused qkv row stride (4096 Q | 1024 K | 1024 V)

__device__ __forceinline__ u16 f2bf(float f) {
  u32 u = __float_as_uint(f);
  u32 r = (u + 0x7FFFu + ((u >> 16) & 1u)) >> 16;
  return (u16)r;
}
__device__ __forceinline__ float bf2f(u16 v) {
  return __uint_as_float(((u32)v) << 16);
}
__device__ __forceinline__ f32x4 mfma16(bf16x8 a, bf16x8 b, f32x4 c) {
  return __builtin_amdgcn_mfma_f32_16x16x32_bf16(a, b, c, 0, 0, 0);
}
// async global->LDS, 16B per lane. LDS dest is wave-uniform base + lane*16.
__device__ __forceinline__ void async16(const u16* g, u16* l) {
  __builtin_amdgcn_global_load_lds(
      (__attribute__((address_space(1))) void*)g,
      (__attribute__((address_space(3))) void*)l, 16, 0, 0);
}
#if __has_builtin(__builtin_amdgcn_exp2f)
#define EXP2(x) __builtin_amdgcn_exp2f(x)
#else
#define EXP2(x) exp2f(x)
#endif

#define VMC(n) asm volatile("s_waitcnt vmcnt(" #n ")" ::: "memory")
#define BAR __builtin_amdgcn_s_barrier()
#define CFENCE asm volatile("" ::: "memory")

// ---------------- fp32 -> bf16 for hidden_states only ------------------------
__global__ __launch_bounds__(256) void conv_hs(const float* __restrict__ hs,
                                               u16* __restrict__ dst) {
  int i = blockIdx.x * 256 + threadIdx.x;
  float4 v = ((const float4*)hs)[i];
  ushort4 o;
  o.x = f2bf(v.x); o.y = f2bf(v.y); o.z = f2bf(v.z); o.w = f2bf(v.w);
  ((ushort4*)dst)[i] = o;
}

// ---------------- 256xBN 4-phase GEMM, fp32-B direct (no weight conv) -------
// C[M,N] = A[M,K] * B[N,K]^T.  A bf16 (gload_lds path, unchanged from R7);
// B fp32 read DIRECTLY from the input weight tensors, reg-staged:
// global_load_dwordx4 -> f2bf -> swizzled ds_write_b64 producing the IDENTICAL
// bf16 LDS layout (slot = chunk ^ (row&7)) the DS-read side expects.
// B rows select among W0|W1|W2 at boundaries nb1/nb2 (per-lane pointer,
// computed once).  De-caged scheduling (R7 win): barriers + counted VMC only.
// Publication: every B ds_write is >=2 barriers ahead of its consumer, and
// the writer's lgkm retires via the NEXT pre-phase's ds-read wait (in-order
// lgkm); prologue drains lgkm explicitly once.
// Ledger: pre-ph1 ldB(t+1)+wrB->d1 (cvt drains A(t+1), issued 2 phases ago);
// pre-ph2 ldB(t+2) + A(t+2) gload (VMCP2 = leave all 2NJ+4 newest);
// pre-ph3 wrB(t+2)->d0 (cvt waits only B loads, A(t+2) stays in flight);
// pre-ph4 A(t+3) gload + VMC(4) drains A(t+2).
// Grid = 8 * (N/BN); M == 2048 -> 8 M-tiles; %8 == 0 for the XCD swizzle.

#define DSA(dst, qi, d)                                                    \
  {                                                                        \
    const u16* p_ = As + (d)*16384 + (wm * 64 + (qi)*32 + cl) * 64;        \
    _Pragma("unroll") for (int ii = 0; ii < 2; ii++)                       \
        _Pragma("unroll") for (int kk = 0; kk < 2; kk++)                   \
            dst[ii][kk] =                                                  \
        *(const bf16x8*)(p_ + ii * 1024 + ((c0 ^ (kk << 2)) << 3));        \
  }

#define DSB(dst, qj, d)                                                    \
  {                                                                        \
    const u16* p_ =                                                        \
        Bs + (d)*BSTR + (wn * (BN / 2) + (qj) * (BN / 4) + cl) * 64;       \
    _Pragma("unroll") for (int jj = 0; jj < NJ; jj++)                      \
        _Pragma("unroll") for (int kk = 0; kk < 2; kk++)                   \
            dst[jj][kk] =                                                  \
        *(const bf16x8*)(p_ + jj * 1024 + ((c0 ^ (kk << 2)) << 3));        \
  }

// kk outermost: consecutive MFMAs hit distinct acc regs
#define MM(qi, qj, asrc, bsrc)                                             \
  {                                                                        \
    _Pragma("unroll") for (int kk = 0; kk < 2; kk++)                       \
        _Pragma("unroll") for (int ii = 0; ii < 2; ii++)                   \
            _Pragma("unroll") for (int jj = 0; jj < NJ; jj++)              \
                acc[(qi)*2 + ii][(qj)*NJ + jj] =                           \
        mfma16(asrc[ii][kk], bsrc[jj][kk], acc[(qi)*2 + ii][(qj)*NJ + jj]);\
  }

#define PH2(MMA1, MMA2)                                          \
  {                                                              \
    BAR;                                                         \
    MMA1; MMA2;                                                  \
    BAR;                                                         \
  }

#define VMCP2()                             \
  do {                                      \
    if constexpr (NJ == 3) VMC(10);         \
    else VMC(8);                            \
  } while (0)

template <int NJ>
__global__ __launch_bounds__(512, 2) void gemm4p(
    const u16* __restrict__ A, const float* __restrict__ W0,
    const float* __restrict__ W1, const float* __restrict__ W2,
    int nb1, int nb2, u16* __restrict__ Cb, float* __restrict__ Cf,
    int N, int K) {
  constexpr int BN = NJ * 64;
  constexpr int BSTR = BN * 64;  // u16 per B dbuf
  extern __shared__ u16 lds[];
  u16* As = lds;           // [2][256*64]
  u16* Bs = lds + 32768;   // [2][BN*64]
  const int tid = threadIdx.x;
  const int lane = tid & 63, wv = tid >> 6;
  const int cl = lane & 15, qd = lane >> 4;
  const int wm = wv >> 1, wn = wv & 1;  // 4M x 2N waves
  const int c0 = qd ^ (cl & 7);

  // XCD-aware block swizzle (grid %8==0), decode M-fast (M-tiles == 8)
  const int cpx = gridDim.x >> 3;
  const int swz = (blockIdx.x & 7) * cpx + (blockIdx.x >> 3);
  const int m0 = (swz & 7) * 256;
  const int n0 = (swz >> 3) * BN;

  // A staging offsets (bf16 gload_lds, pre-swizzled source; lane covers LDS
  // (row r, slot s), fetches global chunk c = s ^ (r&7))
  u32 aof[4];
#pragma unroll
  for (int q = 0; q < 4; q++) {
    int r = q * 64 + wv * 8 + (lane >> 3);
    int c = (lane & 7) ^ (r & 7);
    aof[q] = (u32)(m0 + r) * K + c * 8;
  }
  const int sbo = wv * 512;  // wave-uniform LDS stage offset

  // B staging: 2*NJ rounds; round rq covers row rl = rq*32 + (tid>>4),
  // f32-chunk gc = tid&15 (16B).  Output bf16 chunk c = gc>>1, half = gc&1;
  // swizzled ds_write slot = c ^ (rl&7).
  const float* bptr[2 * NJ];
  u32 bwr[2 * NJ];
#pragma unroll
  for (int rq = 0; rq < 2 * NJ; rq++) {
    int rl = rq * 32 + (tid >> 4);
    int gc = tid & 15;
    int row = n0 + rl;
    const float* p = (row < nb1) ? (W0 + (size_t)row * K)
                   : (row < nb2) ? (W1 + (size_t)(row - nb1) * K)
                                 : (W2 + (size_t)(row - nb2) * K);
    bptr[rq] = p + gc * 4;
    bwr[rq] = (u32)rl * 64 + (((gc >> 1) ^ (rl & 7)) * 8) + ((gc & 1) * 4);
  }

  auto STAll = [&](int tt, int d) {  // stage full A K-tile (4 gload_lds)
#pragma unroll
    for (int q = 0; q < 4; q++)
      async16(A + (size_t)tt * 64 + aof[q], As + d * 16384 + q * 4096 + sbo);
  };

  float4 bv[2 * NJ];
  auto ldB = [&]() {  // issue the 2*NJ fp32 loads for the next B tile
#pragma unroll
    for (int rq = 0; rq < 2 * NJ; rq++) {
      bv[rq] = *(const float4*)bptr[rq];
      bptr[rq] += 64;  // advance one K-tile (64 f32)
    }
  };
  auto wrB = [&](int d) {  // convert + swizzled ds_write into dbuf d
#pragma unroll
    for (int rq = 0; rq < 2 * NJ; rq++) {
      u32 lo = (u32)f2bf(bv[rq].x) | ((u32)f2bf(bv[rq].y) << 16);
      u32 hi = (u32)f2bf(bv[rq].z) | ((u32)f2bf(bv[rq].w) << 16);
      uint2 wd;
      wd.x = lo;
      wd.y = hi;
      *(uint2*)(Bs + d * BSTR + bwr[rq]) = wd;  // ds_write_b64
    }
    CFENCE;
  };

  f32x4 acc[4][2 * NJ];
  f32x4 zz = {0.f, 0.f, 0.f, 0.f};
#pragma unroll
  for (int i = 0; i < 4; i++)
#pragma unroll
    for (int j = 0; j < 2 * NJ; j++) acc[i][j] = zz;
  bf16x8 A0r[2][2], A1r[2][2], B0r[NJ][2], B1r[NJ][2];

  const int NT = K >> 6;  // 64-wide K-tiles; NT even, >= 4

  // prologue: A(0)->d0, A(1)->d1 (gload); B(0)->d0 (reg-staged).
  STAll(0, 0);
  STAll(1, 1);
  ldB();
  wrB(0);
  VMC(4);  // A(0) landed; A(1) stays in flight
  asm volatile("s_waitcnt lgkmcnt(0)" ::: "memory");  // publish B(0) writes
  BAR;

  for (int it = 0; it < (NT >> 1); ++it) {
    const int t = it * 2;          // tiles t (dbuf0), t+1 (dbuf1)
    const bool s2 = (t + 2) < NT;  // NT even => also guards t+3
    // pre-ph1: ldB(t+1) | ds reads dbuf0 | wrB(t+1)->d1 (freed prev ph4)
    ldB();
    DSA(A0r, 0, 0); DSA(A1r, 1, 0); DSB(B0r, 0, 0);
    wrB(1);
    PH2(MM(0, 0, A0r, B0r), MM(1, 0, A1r, B0r));
    // pre-ph2: ds B1(dbuf0) | ldB(t+2) issue-early | A(t+2) gload -> d0
    DSB(B1r, 1, 0);
    if (s2) {
      ldB();
      STAll(t + 2, 0);
      VMCP2();
    } else {
      VMC(0);
    }
    PH2(MM(0, 1, A0r, B1r), MM(1, 1, A1r, B1r));
    // pre-ph3: ds reads dbuf1 | wrB(t+2)->d0 (cvt waits only the B loads;
    //          A(t+2) gloads are newer and stay in flight)
    DSA(A0r, 0, 1); DSA(A1r, 1, 1); DSB(B0r, 0, 1);
    if (s2) wrB(0);
    PH2(MM(0, 0, A0r, B0r), MM(1, 0, A1r, B0r));
    // pre-ph4: ds B1(dbuf1) | A(t+3) gload -> d1 | VMC(4) drains A(t+2)
    DSB(B1r, 1, 1);
    if (s2) {
      STAll(t + 3, 1);
      VMC(4);
    } else {
      VMC(0);
    }
    PH2(MM(0, 1, A0r, B1r), MM(1, 1, A1r, B1r));
  }

  // epilogue: C-write (C/D layout: col=lane&15, row=(lane>>4)*4+reg)
#pragma unroll
  for (int i = 0; i < 4; i++)
#pragma unroll
    for (int j = 0; j < 2 * NJ; j++) {
      int row = m0 + wm * 64 + i * 16 + qd * 4;
      int col = n0 + wn * (BN / 2) + (j / NJ) * (BN / 4) + (j % NJ) * 16 + cl;
#pragma unroll
      for (int r = 0; r < 4; r++) {
        float v = acc[i][j][r];
        if (Cb) Cb[(size_t)(row + r) * N + col] = f2bf(v);
        else    Cf[(size_t)(row + r) * N + col] = v;
      }
    }
}

// ---------------- fused RoPE + L2 norm (in place, bf16, strided) -------------
__global__ __launch_bounds__(256) void rope_l2norm(
    u16* __restrict__ x, const int* __restrict__ pos_ids,
    const float* __restrict__ scale, int hmask, int hshift, int stride) {
  const int lane = threadIdx.x & 63;
  const int wv = threadIdx.x >> 6;
  const int idx = blockIdx.x * 4 + wv;
  const int s = idx >> hshift;
  const int h = idx & hmask;
  u16* p = x + (size_t)s * stride + h * HD;
  const float pos = (float)pos_ids[s];
  const float inv = expf((float)lane * -0.20503692777194264f);  // 5e5^(-d/64)
  float sn, cs;
  sincosf(pos * inv, &sn, &cs);
  float a = bf2f(p[lane]);
  float b = bf2f(p[lane + 64]);
  float ra = a * cs - b * sn;
  float rb = b * cs + a * sn;
  float ss = ra * ra + rb * rb;
#pragma unroll
  for (int off = 32; off >= 1; off >>= 1) ss += __shfl_xor(ss, off, 64);
  float rd = 1.0f / (sqrtf(ss) + 1e-6f);
  p[lane] = f2bf(scale[lane] * ra * rd);
  p[lane + 64] = f2bf(scale[lane + 64] * rb * rd);
}

// ---------------- V transpose: qkv V-cols [2048][1024@QS] -> [1024][2048] ----
__global__ __launch_bounds__(256) void transpose_v(const u16* __restrict__ v,
                                                   u16* __restrict__ vt) {
  __shared__ u16 t[64][65];
  const int r = threadIdx.x >> 6;
  const int c = threadIdx.x & 63;
  const int s0 = blockIdx.x * 64, d0 = blockIdx.y * 64;
#pragma unroll
  for (int i = 0; i < 16; i++) {
    int row = i * 4 + r;
    t[row][c] = v[(size_t)(s0 + row) * QS + d0 + c];
  }
  __syncthreads();
#pragma unroll
  for (int i = 0; i < 16; i++) {
    int row = i * 4 + r;
    vt[(size_t)(d0 + row) * S_LEN + s0 + c] = t[c][row];
  }
}

// ---------------- causal flash attention, Q-tile 128, 8 waves ----------------
// Work-balanced (qbi, 15-qbi) pairs, grid 8 x 32 = 256 blocks = 1/CU.
// K/V double-buffered in dynamic LDS; stage(kt+1) issued BEFORE compute(kt)
// (issue-early / wait-late): one vmcnt(0)+barrier per tile, stage latency
// hidden under a full compute phase.  No sched fences (compiler-scheduled).
#define PLD 68

__global__ __launch_bounds__(512) void flash_attn(
    const u16* __restrict__ QKV, const u16* __restrict__ Vt,
    u16* __restrict__ O) {
  extern __shared__ u16 alds[];
  u16* Ks = alds;           // [2][64*128]  slot = row*16 + (g ^ (row&15))
  u16* Vs = alds + 16384;   // [2][128*64]  slot = row*8  + (g ^ (row&7))
  u16* Ps = alds + 32768;   // [128][PLD]
  const int tid = threadIdx.x;
  const int lane = tid & 63, wv = tid >> 6;  // wv in [0,8)
  const int cl = lane & 15, qd = lane >> 4;
  const int h = blockIdx.y;
  const int kvh = h >> 2;
  const float es = 0.12751629240081506f;  // (1/sqrt(128)) * log2(e)

  const u16* Kbase = QKV + 4096 + kvh * HD;          // key rows, stride QS
  const u16* Vbase = Vt + (size_t)kvh * HD * S_LEN;  // [d][s], stride S_LEN

  auto stage = [&](int kt, int d) {
#pragma unroll
    for (int q = 0; q < 2; q++) {
      int c = q * 512 + wv * 64 + lane;
      int kr = c >> 4, kg = (c & 15) ^ (kr & 15);
      async16(Kbase + (size_t)(kt * 64 + kr) * QS + kg * 8,
              Ks + d * 8192 + (q * 512 + wv * 64) * 8);
      int vr = c >> 3, vg = (c & 7) ^ (vr & 7);
      async16(Vbase + (size_t)vr * S_LEN + kt * 64 + vg * 8,
              Vs + d * 8192 + (q * 512 + wv * 64) * 8);
    }
  };

  for (int half = 0; half < 2; half++) {
    const int qbi = half ? (15 - (int)blockIdx.x) : (int)blockIdx.x;
    const int q0 = qbi * 128;

    // Q fragments straight from global; wave wv owns q-rows q0+wv*16 .. +15
    bf16x8 aQ[4];
    {
      const u16* qrow =
          QKV + (size_t)(q0 + wv * 16 + cl) * QS + h * HD + qd * 8;
#pragma unroll
      for (int kk = 0; kk < 4; kk++) aQ[kk] = *(const bf16x8*)(qrow + kk * 32);
    }

    f32x4 oacc[8];
    f32x4 zz = {0.f, 0.f, 0.f, 0.f};
#pragma unroll
    for (int n = 0; n < 8; n++) oacc[n] = zz;
    float lsum[4] = {0.f, 0.f, 0.f, 0.f};

    const int row_min = q0 + wv * 16;
    const int ktmax = 2 * qbi + 1;  // >= 1 always

    int cur = 0;
    stage(0, 0);
    for (int kt = 0; kt <= ktmax; kt++) {
      if (kt < ktmax) stage(kt + 1, cur ^ 1);  // issue-early
      if (kt == 0) {
        VMC(4);  // tile0 landed; tile1's 4 loads stay in flight
        BAR;
      }
      const int koff = cur * 8192;

      if (kt * 64 <= row_min + 15) {  // wave not fully above the diagonal
        // S = Q K^T (this wave: 16 q-rows x 64 keys); kk outer -> indep runs
        f32x4 sacc[4];
#pragma unroll
        for (int j = 0; j < 4; j++) sacc[j] = zz;
#pragma unroll
        for (int kk = 0; kk < 4; kk++) {
#pragma unroll
          for (int j = 0; j < 4; j++) {
            int row = j * 16 + cl;
            int ch = (kk * 4 + qd) ^ (row & 15);
            bf16x8 bK = *(const bf16x8*)&Ks[koff + row * 128 + ch * 8];
            sacc[j] = mfma16(aQ[kk], bK, sacc[j]);
          }
        }

        float pm[4][4];
        if (kt * 64 + 63 > row_min) {  // diagonal tile: causal mask
          const int grow = row_min + qd * 4;
#pragma unroll
          for (int j = 0; j < 4; j++) {
            int gcol = kt * 64 + j * 16 + cl;
#pragma unroll
            for (int r = 0; r < 4; r++)
              pm[j][r] = (gcol <= grow + r) ? EXP2(sacc[j][r] * es) : 0.f;
          }
        } else {
#pragma unroll
          for (int j = 0; j < 4; j++)
#pragma unroll
            for (int r = 0; r < 4; r++) pm[j][r] = EXP2(sacc[j][r] * es);
        }
#pragma unroll
        for (int j = 0; j < 4; j++)
#pragma unroll
          for (int r = 0; r < 4; r++) lsum[r] += pm[j][r];

        // P: C-layout -> LDS (A-layout); wave-private strip, no block barrier
#pragma unroll
        for (int j = 0; j < 4; j++)
#pragma unroll
          for (int r = 0; r < 4; r++)
            Ps[(wv * 16 + qd * 4 + r) * PLD + j * 16 + cl] = f2bf(pm[j][r]);
        __asm__ volatile("s_waitcnt lgkmcnt(0)" ::: "memory");  // cross-lane

        // O += P V (n inner: dep distance 8)
#pragma unroll
        for (int kk = 0; kk < 2; kk++) {
          bf16x8 aP =
              *(const bf16x8*)&Ps[(wv * 16 + cl) * PLD + kk * 32 + qd * 8];
#pragma unroll
          for (int n = 0; n < 8; n++) {
            int row = n * 16 + cl;
            int ch = (kk * 4 + qd) ^ (row & 7);
            bf16x8 bV = *(const bf16x8*)&Vs[koff + row * 64 + ch * 8];
            oacc[n] = mfma16(aP, bV, oacc[n]);
          }
        }
      }

      VMC(0);  // stage(kt+1) drained (latency hidden under compute)
      BAR;
      cur ^= 1;
    }

    // reduce row sums across the 16-lane column group, write O
#pragma unroll
    for (int r = 0; r < 4; r++) {
#pragma unroll
      for (int off = 8; off >= 1; off >>= 1)
        lsum[r] += __shfl_xor(lsum[r], off, 64);
    }
#pragma unroll
    for (int r = 0; r < 4; r++) {
      float il = 1.0f / lsum[r];
      int row = row_min + qd * 4 + r;
#pragma unroll
      for (int n = 0; n < 8; n++)
        O[(size_t)row * HID + h * HD + n * 16 + cl] = f2bf(oacc[n][r] * il);
    }
  }
}

// ---------------- launch ----------------
extern "C" void kernel_launch(void* const* d_in, const int* in_sizes, int n_in,
                              void* d_out, int out_size, void* d_ws, size_t ws_size,
                              hipStream_t stream) {
  const float* hs = (const float*)d_in[0];
  const int* pos = (const int*)d_in[1];
  const float* Wq = (const float*)d_in[2];
  const float* Wk = (const float*)d_in[3];
  const float* Wv = (const float*)d_in[4];
  const float* Wo = (const float*)d_in[5];
  const float* qsc = (const float*)d_in[6];
  const float* ksc = (const float*)d_in[7];
  float* out = (float*)d_out;
  char* ws = (char*)d_ws;
  const size_t MB = 1u << 20;

  u16* hs_b  = (u16*)(ws + 0 * MB);   // 16 MB; reused for attention output
  u16* qkv_b = (u16*)(ws + 64 * MB);  // 24 MB: [2048][6144] = Q|K|V
  u16* vt_b  = (u16*)(ws + 88 * MB);  // 4 MB: V^T [1024][2048]
  u16* o_b   = hs_b;                  // hs dead after qkv gemm

  static bool attr_set = false;
  if (!attr_set) {
    hipFuncSetAttribute(reinterpret_cast<const void*>(&gemm4p<3>),
                        hipFuncAttributeMaxDynamicSharedMemorySize, 114688);
    hipFuncSetAttribute(reinterpret_cast<const void*>(&gemm4p<2>),
                        hipFuncAttributeMaxDynamicSharedMemorySize, 98304);
    hipFuncSetAttribute(reinterpret_cast<const void*>(&flash_attn),
                        hipFuncAttributeMaxDynamicSharedMemorySize, 82944);
    attr_set = true;
  }

  // hs fp32 -> bf16 (weights are consumed fp32 directly by the GEMMs)
  conv_hs<<<8192, 256, 0, stream>>>(hs, hs_b);

  // fused QKV projection: [2048][4096] x [6144][4096]^T -> [2048][6144]
  // B rows 0..4095 = Wq, 4096..5119 = Wk, 5120..6143 = Wv (fp32 direct)
  gemm4p<3><<<dim3(8 * (QS / 192)), 512, 114688, stream>>>(
      hs_b, Wq, Wk, Wv, 4096, 5120, qkv_b, nullptr, QS, HID);

  rope_l2norm<<<S_LEN * NH / 4, 256, 0, stream>>>(qkv_b, pos, qsc, NH - 1, 5, QS);
  rope_l2norm<<<S_LEN * NKV / 4, 256, 0, stream>>>(qkv_b + 4096, pos, ksc, NKV - 1, 3, QS);
  transpose_v<<<dim3(S_LEN / 64, (NKV * HD) / 64), 256, 0, stream>>>(qkv_b + 5120, vt_b);

  flash_attn<<<dim3(8, NH), 512, 82944, stream>>>(qkv_b, vt_b, o_b);

  // output projection: [2048][4096] x [4096][4096]^T -> f32 out (Wo fp32)
  gemm4p<2><<<dim3(8 * (HID / 128)), 512, 98304, stream>>>(
      o_b, Wo, Wo, Wo, HID, HID, nullptr, out, HID, HID);
}